// Round 8
// baseline (2774.590 us; speedup 1.0000x reference)
//
#include <hip/hip_runtime.h>
#include <cmath>

// Problem constants (B,N,DIM,HEADS)=(4,4096,1024,16), SX=SY=2, ratio .9
#define B_  4
#define N_  4096
#define C_  1024
#define H_  16
#define D_  64
#define ND_ 1024   // num dst tokens (one per 2x2 block)
#define NA_ 3072   // num src (a) tokens
// r = min(3072, int(4096*0.9)) = 3072  => unm empty, sort permutation cancels.

// ---------------------------------------------------------------------------
// threefry2x32 (20 rounds), returns BOTH output words.
// ---------------------------------------------------------------------------
__device__ inline void tf2x32(unsigned k0, unsigned k1, unsigned x0, unsigned x1,
                              unsigned& o0, unsigned& o1) {
  const unsigned ks2 = 0x1BD11BDAu ^ k0 ^ k1;
  x0 += k0; x1 += k1;
#define RND_(r) { x0 += x1; x1 = (x1 << (r)) | (x1 >> (32 - (r))); x1 ^= x0; }
  RND_(13) RND_(15) RND_(26) RND_(6)
  x0 += k1;  x1 += ks2 + 1u;
  RND_(17) RND_(29) RND_(16) RND_(24)
  x0 += ks2; x1 += k0 + 2u;
  RND_(13) RND_(15) RND_(26) RND_(6)
  x0 += k0;  x1 += k1 + 3u;
  RND_(17) RND_(29) RND_(16) RND_(24)
  x0 += k1;  x1 += ks2 + 4u;
  RND_(13) RND_(15) RND_(26) RND_(6)
  x0 += ks2; x1 += k0 + 5u;
#undef RND_
  o0 = x0; o1 = x1;
}

// ---------------------------------------------------------------------------
// K1 (VERIFIED r7): jax.random.randint(key(33),(32,32),0,4):
// k2 = split(key)[1] = threefry_out((0,33),(0,1)); element p ->
// threefry(k2,(0,p)), value = (bits1^bits2) & 3.
// ---------------------------------------------------------------------------
__global__ __launch_bounds__(1024) void k_init_indices(int* __restrict__ b_idx,
                                                       int* __restrict__ a_idx) {
  __shared__ unsigned char randk[1024];
  __shared__ int wtot[16], wpre[16];
  const int tid = threadIdx.x;
  {
    unsigned c0, c1;
    tf2x32(0u, 33u, 0u, 1u, c0, c1);                 // k2 = split(key)[1]
    unsigned d0, d1;
    tf2x32(c0, c1, 0u, (unsigned)tid, d0, d1);       // random_bits element p
    randk[tid] = (unsigned char)((d0 ^ d1) & 3u);    // xor-fold, % span
  }
  __syncthreads();
  const int base_t = tid * 4;
  int f[4]; int cnt = 0;
#pragma unroll
  for (int j = 0; j < 4; j++) {
    const int t = base_t + j;
    const int y = t >> 6, xc = t & 63;
    const int bi = (y >> 1) * 32 + (xc >> 1);
    const int k  = (y & 1) * 2 + (xc & 1);
    f[j] = (randk[bi] == (unsigned char)k) ? 1 : 0;
    cnt += f[j];
  }
  const int lane = tid & 63, wave = tid >> 6;
  int incl = cnt;
#pragma unroll
  for (int off = 1; off < 64; off <<= 1) {
    int nb = __shfl_up(incl, off, 64);
    if (lane >= off) incl += nb;
  }
  if (lane == 63) wtot[wave] = incl;
  __syncthreads();
  if (tid == 0) { int s = 0; for (int w = 0; w < 16; w++) { wpre[w] = s; s += wtot[w]; } }
  __syncthreads();
  int P = wpre[wave] + (incl - cnt);   // #dst strictly before base_t
#pragma unroll
  for (int j = 0; j < 4; j++) {
    const int t = base_t + j;
    if (f[j]) { b_idx[P] = t; P++; }
    else      { a_idx[t - P] = t; }
  }
}

// ---------------------------------------------------------------------------
// K2: per-token inverse L2 norm of x, fp64
// ---------------------------------------------------------------------------
__global__ __launch_bounds__(256) void k_row_norms(const float* __restrict__ x,
                                                   double* __restrict__ dinv) {
  const int row = blockIdx.x;                 // B_*N_
  const float* xr = x + (size_t)row * C_;
  const int tid = threadIdx.x;
  float4 v = ((const float4*)xr)[tid];
  double s = (double)v.x * (double)v.x + (double)v.y * (double)v.y +
             (double)v.z * (double)v.z + (double)v.w * (double)v.w;
#pragma unroll
  for (int off = 32; off; off >>= 1) s += __shfl_down(s, off, 64);
  __shared__ double wsum[4];
  if ((tid & 63) == 0) wsum[tid >> 6] = s;
  __syncthreads();
  if (tid == 0) {
    double t = wsum[0] + wsum[1] + wsum[2] + wsum[3];
    dinv[row] = 1.0 / sqrt(t);
  }
}

__device__ inline void top2_merge(float& v1, int& i1, float& v2,
                                  float ov1, int oi1, float ov2) {
  const bool take = (ov1 > v1) || (ov1 == v1 && oi1 < i1);
  const float nv2 = take ? fmaxf(v1, ov2) : fmaxf(v2, ov1);
  if (take) { v1 = ov1; i1 = oi1; }
  v2 = nv2;
}

// ---------------------------------------------------------------------------
// K3: fp32 scores 64x64 tile GEMM, top-2 epilogue (argmax ties resolved by
// K5's fp64 recheck; proven identical to full-fp64 argmax in r1/r2).
// ---------------------------------------------------------------------------
__global__ __launch_bounds__(256) void k_scores(
    const float* __restrict__ x, const double* __restrict__ dinv,
    const int* __restrict__ a_idx, const int* __restrict__ b_idx,
    float* __restrict__ pv1, int* __restrict__ pi1, float* __restrict__ pv2) {
  __shared__ __align__(16) float As[16][68];
  __shared__ __align__(16) float Bs[16][68];
  const int bz = blockIdx.z, cb = blockIdx.x, sb = blockIdx.y;
  const int tid = threadIdx.x;
  const int tx = tid & 15, ty = tid >> 4;
  const int lm = tid >> 2, lk = (tid & 3) * 4;
  const int ga = a_idx[sb * 64 + lm];
  const int gb = b_idx[cb * 64 + lm];
  const float ia = (float)dinv[bz * N_ + ga];
  const float ib = (float)dinv[bz * N_ + gb];
  const float* __restrict__ xa = x + ((size_t)bz * N_ + ga) * C_;
  const float* __restrict__ xb = x + ((size_t)bz * N_ + gb) * C_;
  float acc[4][4] = {};
  for (int k0 = 0; k0 < C_; k0 += 16) {
    const float4 av = *(const float4*)(xa + k0 + lk);
    const float4 bv = *(const float4*)(xb + k0 + lk);
    __syncthreads();
    As[lk + 0][lm] = av.x * ia; As[lk + 1][lm] = av.y * ia;
    As[lk + 2][lm] = av.z * ia; As[lk + 3][lm] = av.w * ia;
    Bs[lk + 0][lm] = bv.x * ib; Bs[lk + 1][lm] = bv.y * ib;
    Bs[lk + 2][lm] = bv.z * ib; Bs[lk + 3][lm] = bv.w * ib;
    __syncthreads();
#pragma unroll
    for (int k = 0; k < 16; k++) {
      const float4 a4 = *(const float4*)&As[k][ty * 4];
      const float4 b4 = *(const float4*)&Bs[k][tx * 4];
      const float ar[4] = {a4.x, a4.y, a4.z, a4.w};
      const float br[4] = {b4.x, b4.y, b4.z, b4.w};
#pragma unroll
      for (int i = 0; i < 4; i++)
#pragma unroll
        for (int j = 0; j < 4; j++) acc[i][j] = fmaf(ar[i], br[j], acc[i][j]);
    }
  }
#pragma unroll
  for (int i = 0; i < 4; i++) {
    float v1 = acc[i][0]; int i1 = cb * 64 + tx * 4; float v2 = -INFINITY;
#pragma unroll
    for (int j = 1; j < 4; j++) {
      const float v = acc[i][j];
      if (v > v1) { v2 = v1; v1 = v; i1 = cb * 64 + tx * 4 + j; }
      else if (v > v2) v2 = v;
    }
#pragma unroll
    for (int off = 8; off; off >>= 1) {
      const float ov1 = __shfl_xor(v1, off, 16);
      const int   oi1 = __shfl_xor(i1, off, 16);
      const float ov2 = __shfl_xor(v2, off, 16);
      top2_merge(v1, i1, v2, ov1, oi1, ov2);
    }
    if (tx == 0) {
      const int s = sb * 64 + ty * 4 + i;
      const size_t o = ((size_t)bz * NA_ + s) * 16 + cb;
      pv1[o] = v1; pi1[o] = i1; pv2[o] = v2;
    }
  }
}

// K4: merge 16 per-tile partials -> node_idx + near-tie flag
__global__ __launch_bounds__(256) void k_finalize(
    const float* __restrict__ pv1, const int* __restrict__ pi1,
    const float* __restrict__ pv2, int* __restrict__ node_idx,
    int* __restrict__ flagr) {
  const int r = blockIdx.x * 256 + threadIdx.x;   // [0, B_*NA_)
  if (r >= B_ * NA_) return;
  size_t o = (size_t)r * 16;
  float v1 = pv1[o]; int i1 = pi1[o]; float v2 = pv2[o];
  for (int cb = 1; cb < 16; cb++) top2_merge(v1, i1, v2, pv1[o + cb], pi1[o + cb], pv2[o + cb]);
  node_idx[r] = i1;
  flagr[r] = (v1 - v2 < 3e-4f) ? 1 : 0;  // fp32 GEMM error << 3e-4
}

// K5: exact fp64 argmax for flagged rows (one block per row; most exit).
__global__ __launch_bounds__(256) void k_recheck(
    const float* __restrict__ x, const double* __restrict__ dinv,
    const int* __restrict__ a_idx, const int* __restrict__ b_idx,
    const int* __restrict__ flagr, int* __restrict__ node_idx) {
  const int r = blockIdx.x;                 // bz*NA_ + s
  if (!flagr[r]) return;
  const int bz = r / NA_, s = r % NA_;
  __shared__ double arow[C_];
  const int ga = a_idx[s];
  const double ia = dinv[bz * N_ + ga];
  const float* xa = x + ((size_t)bz * N_ + ga) * C_;
  for (int c = threadIdx.x; c < C_; c += 256) arow[c] = (double)xa[c] * ia;
  __syncthreads();
  const int lane = threadIdx.x & 63, wave = threadIdx.x >> 6;
  double bv = -1e300; int bi = 1 << 30;
  for (int dit = 0; dit < ND_ / 4; dit++) {
    const int d = dit * 4 + wave;
    const int gb = b_idx[d];
    const double ib = dinv[bz * N_ + gb];
    const float* xb = x + ((size_t)bz * N_ + gb) * C_;
    double sum = 0.0;
    for (int c = lane; c < C_; c += 64) sum += arow[c] * ((double)xb[c] * ib);
#pragma unroll
    for (int off = 32; off; off >>= 1) sum += __shfl_xor(sum, off, 64);
    if (sum > bv || (sum == bv && d < bi)) { bv = sum; bi = d; }
  }
  __shared__ double bvs[4]; __shared__ int bis[4];
  if (lane == 0) { bvs[wave] = bv; bis[wave] = bi; }
  __syncthreads();
  if (threadIdx.x == 0) {
    for (int w = 1; w < 4; w++)
      if (bvs[w] > bv || (bvs[w] == bv && bis[w] < bi)) { bv = bvs[w]; bi = bis[w]; }
    node_idx[r] = bi;
  }
}

// K6: counts per dst + token->merged-row map
__global__ __launch_bounds__(256) void k_counts_rowmap(
    const int* __restrict__ a_idx, const int* __restrict__ b_idx,
    const int* __restrict__ node_idx, int* __restrict__ cnt,
    int* __restrict__ rowmap) {
  const int i = blockIdx.x * 256 + threadIdx.x;   // [0, B_*N_)
  if (i >= B_ * N_) return;
  const int bz = i >> 12, j = i & 4095;
  if (j < NA_) {
    const int nd = node_idx[bz * NA_ + j];
    atomicAdd(&cnt[bz * ND_ + nd], 1);
    rowmap[bz * N_ + a_idx[j]] = nd;
  } else {
    const int d = j - NA_;
    rowmap[bz * N_ + b_idx[d]] = d;
  }
}

// K7/K8/K9: merge x into xm
__global__ __launch_bounds__(256) void k_merge_init(const float* __restrict__ x,
                                                    const int* __restrict__ b_idx,
                                                    float* __restrict__ xm) {
  const int blk = blockIdx.x;                 // B_*ND_
  const int bz = blk >> 10, d = blk & 1023;
  const float4* src = (const float4*)(x + ((size_t)bz * N_ + b_idx[d]) * C_);
  float4* dst = (float4*)(xm + ((size_t)bz * ND_ + d) * C_);
  dst[threadIdx.x] = src[threadIdx.x];
}

__global__ __launch_bounds__(256) void k_merge_add(const float* __restrict__ x,
                                                   const int* __restrict__ a_idx,
                                                   const int* __restrict__ node_idx,
                                                   float* __restrict__ xm) {
  const int blk = blockIdx.x;                 // B_*NA_ = bz*NA_+i
  const int bz = blk / NA_, i = blk % NA_;
  const int nd = node_idx[blk];
  const float* src = x + ((size_t)bz * N_ + a_idx[i]) * C_;
  float* dst = xm + ((size_t)bz * ND_ + nd) * C_;
  const int c0 = threadIdx.x * 4;
  const float4 v = *(const float4*)(src + c0);
  atomicAdd(&dst[c0 + 0], v.x);
  atomicAdd(&dst[c0 + 1], v.y);
  atomicAdd(&dst[c0 + 2], v.z);
  atomicAdd(&dst[c0 + 3], v.w);
}

__global__ __launch_bounds__(256) void k_merge_scale(float* __restrict__ xm,
                                                     const int* __restrict__ cnt) {
  const int blk = blockIdx.x;                 // B_*ND_
  const float s = 1.0f + (float)cnt[blk];
  float4* p = (float4*)(xm + (size_t)blk * C_);
  float4 v = p[threadIdx.x];
  v.x /= s; v.y /= s; v.z /= s; v.w /= s;
  p[threadIdx.x] = v;
}

// ---------------------------------------------------------------------------
// K10: qkv GEMM, 128x128 tile, 8x8 per thread, BK=8.
// qkvm[b][w][h][t][d] = xm @ W_qkv^T   (M=4096, N=3072, K=1024)
// ---------------------------------------------------------------------------
__global__ __launch_bounds__(256) void k_qkv(const float* __restrict__ xm,
                                             const float* __restrict__ Wqkv,
                                             float* __restrict__ qkvm) {
  __shared__ __align__(16) float As[8][132];
  __shared__ __align__(16) float Bs[8][132];
  const int nb = blockIdx.x;   // 24
  const int mb = blockIdx.y;   // 32
  const int tid = threadIdx.x;
  const int tx = tid & 15, ty = tid >> 4;
  const int lr = tid >> 1;            // 0..127
  const int lkc = (tid & 1) * 4;      // 0 or 4
  const float* __restrict__ ar = xm + (size_t)(mb * 128 + lr) * C_ + lkc;
  const float* __restrict__ br = Wqkv + (size_t)(nb * 128 + lr) * C_ + lkc;
  float acc[8][8] = {};
  for (int k0 = 0; k0 < C_; k0 += 8) {
    const float4 av = *(const float4*)(ar + k0);
    const float4 bv = *(const float4*)(br + k0);
    __syncthreads();
    As[lkc + 0][lr] = av.x; As[lkc + 1][lr] = av.y;
    As[lkc + 2][lr] = av.z; As[lkc + 3][lr] = av.w;
    Bs[lkc + 0][lr] = bv.x; Bs[lkc + 1][lr] = bv.y;
    Bs[lkc + 2][lr] = bv.z; Bs[lkc + 3][lr] = bv.w;
    __syncthreads();
#pragma unroll
    for (int k = 0; k < 8; k++) {
      float a_[8], b_[8];
      *(float4*)&a_[0] = *(const float4*)&As[k][ty * 8];
      *(float4*)&a_[4] = *(const float4*)&As[k][ty * 8 + 4];
      *(float4*)&b_[0] = *(const float4*)&Bs[k][tx * 8];
      *(float4*)&b_[4] = *(const float4*)&Bs[k][tx * 8 + 4];
#pragma unroll
      for (int i = 0; i < 8; i++)
#pragma unroll
        for (int j = 0; j < 8; j++) acc[i][j] = fmaf(a_[i], b_[j], acc[i][j]);
    }
  }
  const int n0 = nb * 128 + tx * 8;
  const int w = n0 >> 10, h = (n0 >> 6) & 15, dc = n0 & 63;   // 8 cols within 1 head
#pragma unroll
  for (int i = 0; i < 8; i++) {
    const int m = mb * 128 + ty * 8 + i;
    const int bb = m >> 10, t = m & 1023;
    float* dst = qkvm + (((size_t)(bb * 3 + w) * 16 + h) * 1024 + t) * 64 + dc;
    *(float4*)dst       = make_float4(acc[i][0], acc[i][1], acc[i][2], acc[i][3]);
    *(float4*)(dst + 4) = make_float4(acc[i][4], acc[i][5], acc[i][6], acc[i][7]);
  }
}

// ---------------------------------------------------------------------------
// K11: flash attention, transposed LDS (vector ds_read in both inner loops)
// ---------------------------------------------------------------------------
__global__ __launch_bounds__(256) void k_attn(const float* __restrict__ qkvm,
                                              float* __restrict__ om) {
  __shared__ float qsT[64][65];   // [d][token]
  __shared__ float ksT[64][65];   // [d][token]
  __shared__ float vs[64][65];    // [token][d]
  __shared__ float psT[64][65];   // [kcol][qrow]
  __shared__ float mi[64], li[64];
  const int qb = blockIdx.x, h = blockIdx.y, bz = blockIdx.z;
  const int tid = threadIdx.x;
  const int tx = tid & 15, ty = tid >> 4;
  const float* __restrict__ qp = qkvm + (((size_t)(bz * 3 + 0) * 16 + h) * 1024) * 64;
  const float* __restrict__ kp = qkvm + (((size_t)(bz * 3 + 1) * 16 + h) * 1024) * 64;
  const float* __restrict__ vp = qkvm + (((size_t)(bz * 3 + 2) * 16 + h) * 1024) * 64;
  const int lr = tid >> 2, lc = (tid & 3) * 16;
  {
    const float4* src = (const float4*)(qp + (size_t)(qb * 64 + lr) * 64 + lc);
#pragma unroll
    for (int j = 0; j < 4; j++) {
      const float4 v4 = src[j];
      qsT[lc + j * 4 + 0][lr] = v4.x * 0.125f;
      qsT[lc + j * 4 + 1][lr] = v4.y * 0.125f;
      qsT[lc + j * 4 + 2][lr] = v4.z * 0.125f;
      qsT[lc + j * 4 + 3][lr] = v4.w * 0.125f;
    }
  }
  if (tid < 64) { mi[tid] = -INFINITY; li[tid] = 0.0f; }
  float o[4][4] = {};
  float mnew[4], alpha[4], psum[4];
  for (int kt = 0; kt < 16; kt++) {
    __syncthreads();
    {
      const float4* ksrc = (const float4*)(kp + (size_t)(kt * 64 + lr) * 64 + lc);
      const float4* vsrc = (const float4*)(vp + (size_t)(kt * 64 + lr) * 64 + lc);
#pragma unroll
      for (int j = 0; j < 4; j++) {
        const float4 kv = ksrc[j], vv = vsrc[j];
        ksT[lc + j * 4 + 0][lr] = kv.x; ksT[lc + j * 4 + 1][lr] = kv.y;
        ksT[lc + j * 4 + 2][lr] = kv.z; ksT[lc + j * 4 + 3][lr] = kv.w;
        vs[lr][lc + j * 4 + 0] = vv.x; vs[lr][lc + j * 4 + 1] = vv.y;
        vs[lr][lc + j * 4 + 2] = vv.z; vs[lr][lc + j * 4 + 3] = vv.w;
      }
    }
    __syncthreads();
    float sacc[4][4] = {};
#pragma unroll 4
    for (int c = 0; c < 64; c++) {
      const float4 a4 = *(const float4*)&qsT[c][ty * 4];
      const float4 b4 = *(const float4*)&ksT[c][tx * 4];
      const float a_[4] = {a4.x, a4.y, a4.z, a4.w};
      const float b_[4] = {b4.x, b4.y, b4.z, b4.w};
#pragma unroll
      for (int i = 0; i < 4; i++)
#pragma unroll
        for (int j = 0; j < 4; j++) sacc[i][j] = fmaf(a_[i], b_[j], sacc[i][j]);
    }
#pragma unroll
    for (int i = 0; i < 4; i++) {
      float tmax = fmaxf(fmaxf(sacc[i][0], sacc[i][1]), fmaxf(sacc[i][2], sacc[i][3]));
#pragma unroll
      for (int off = 8; off; off >>= 1) tmax = fmaxf(tmax, __shfl_xor(tmax, off, 16));
      const float mold = mi[ty * 4 + i];
      const float mn = fmaxf(mold, tmax);
      mnew[i] = mn;
      alpha[i] = expf(mold - mn);
      float s_ = 0.0f;
#pragma unroll
      for (int j = 0; j < 4; j++) { sacc[i][j] = expf(sacc[i][j] - mn); s_ += sacc[i][j]; }
#pragma unroll
      for (int off = 8; off; off >>= 1) s_ += __shfl_xor(s_, off, 16);
      psum[i] = s_;
#pragma unroll
      for (int j = 0; j < 4; j++) psT[tx * 4 + j][ty * 4 + i] = sacc[i][j];
    }
    __syncthreads();
    if (tx == 0) {
#pragma unroll
      for (int i = 0; i < 4; i++) {
        mi[ty * 4 + i] = mnew[i];
        li[ty * 4 + i] = li[ty * 4 + i] * alpha[i] + psum[i];
      }
    }
#pragma unroll
    for (int i = 0; i < 4; i++)
#pragma unroll
      for (int j = 0; j < 4; j++) o[i][j] *= alpha[i];
#pragma unroll 4
    for (int d2 = 0; d2 < 64; d2++) {
      const float4 p4 = *(const float4*)&psT[d2][ty * 4];
      const float4 v4 = *(const float4*)&vs[d2][tx * 4];
      const float pr[4] = {p4.x, p4.y, p4.z, p4.w};
      const float vr[4] = {v4.x, v4.y, v4.z, v4.w};
#pragma unroll
      for (int i = 0; i < 4; i++)
#pragma unroll
        for (int j = 0; j < 4; j++) o[i][j] = fmaf(pr[i], vr[j], o[i][j]);
    }
  }
  __syncthreads();
#pragma unroll
  for (int i = 0; i < 4; i++) {
    const float inv = 1.0f / li[ty * 4 + i];
    const int t = qb * 64 + ty * 4 + i;
    const float4 st = make_float4(o[i][0] * inv, o[i][1] * inv, o[i][2] * inv, o[i][3] * inv);
    *(float4*)(om + ((size_t)bz * ND_ + t) * C_ + h * 64 + tx * 4) = st;
  }
}

// ---------------------------------------------------------------------------
// K12: proj GEMM, 128x128 tile, 8x8 per thread, BK=8. ym = om@Wp^T + bp
// ---------------------------------------------------------------------------
__global__ __launch_bounds__(256) void k_proj(const float* __restrict__ om,
                                              const float* __restrict__ Wp,
                                              const float* __restrict__ bp,
                                              float* __restrict__ ym) {
  __shared__ __align__(16) float As[8][132];
  __shared__ __align__(16) float Bs[8][132];
  const int nb = blockIdx.x;   // 8
  const int mb = blockIdx.y;   // 32
  const int tid = threadIdx.x;
  const int tx = tid & 15, ty = tid >> 4;
  const int lr = tid >> 1;
  const int lkc = (tid & 1) * 4;
  const float* __restrict__ ar = om + (size_t)(mb * 128 + lr) * C_ + lkc;
  const float* __restrict__ br = Wp + (size_t)(nb * 128 + lr) * C_ + lkc;
  float acc[8][8] = {};
  for (int k0 = 0; k0 < C_; k0 += 8) {
    const float4 av = *(const float4*)(ar + k0);
    const float4 bv = *(const float4*)(br + k0);
    __syncthreads();
    As[lkc + 0][lr] = av.x; As[lkc + 1][lr] = av.y;
    As[lkc + 2][lr] = av.z; As[lkc + 3][lr] = av.w;
    Bs[lkc + 0][lr] = bv.x; Bs[lkc + 1][lr] = bv.y;
    Bs[lkc + 2][lr] = bv.z; Bs[lkc + 3][lr] = bv.w;
    __syncthreads();
#pragma unroll
    for (int k = 0; k < 8; k++) {
      float a_[8], b_[8];
      *(float4*)&a_[0] = *(const float4*)&As[k][ty * 8];
      *(float4*)&a_[4] = *(const float4*)&As[k][ty * 8 + 4];
      *(float4*)&b_[0] = *(const float4*)&Bs[k][tx * 8];
      *(float4*)&b_[4] = *(const float4*)&Bs[k][tx * 8 + 4];
#pragma unroll
      for (int i = 0; i < 8; i++)
#pragma unroll
        for (int j = 0; j < 8; j++) acc[i][j] = fmaf(a_[i], b_[j], acc[i][j]);
    }
  }
  const int n0 = nb * 128 + tx * 8;
  const float4 b0 = *(const float4*)(bp + n0);
  const float4 b1 = *(const float4*)(bp + n0 + 4);
#pragma unroll
  for (int i = 0; i < 8; i++) {
    const int m = mb * 128 + ty * 8 + i;
    float* dst = ym + (size_t)m * C_ + n0;
    *(float4*)dst       = make_float4(acc[i][0] + b0.x, acc[i][1] + b0.y,
                                      acc[i][2] + b0.z, acc[i][3] + b0.w);
    *(float4*)(dst + 4) = make_float4(acc[i][4] + b1.x, acc[i][5] + b1.y,
                                      acc[i][6] + b1.z, acc[i][7] + b1.w);
  }
}

// K13: scatter merged rows back to all 4096 tokens
__global__ __launch_bounds__(256) void k_unmerge(const float* __restrict__ ym,
                                                 const int* __restrict__ rowmap,
                                                 float* __restrict__ out) {
  const int blk = blockIdx.x;                 // B_*N_
  const int bz = blk >> 12;
  const int r = rowmap[blk];
  const float4* src = (const float4*)(ym + ((size_t)bz * ND_ + r) * C_);
  float4* dst = (float4*)(out + (size_t)blk * C_);
  dst[threadIdx.x] = src[threadIdx.x];
}

// ---------------------------------------------------------------------------
extern "C" void kernel_launch(void* const* d_in, const int* in_sizes, int n_in,
                              void* d_out, int out_size, void* d_ws, size_t ws_size,
                              hipStream_t stream) {
  const float* x    = (const float*)d_in[0];
  const float* Wqkv = (const float*)d_in[1];
  const float* Wp   = (const float*)d_in[2];
  const float* bp   = (const float*)d_in[3];
  char* ws = (char*)d_ws;
  double* dinv    = (double*)(ws + 0);          //  131072 B
  int*   b_idx    = (int*)(ws + 131072);        //    4096 B
  int*   a_idx    = (int*)(ws + 135168);        //   12288 B
  int*   node_idx = (int*)(ws + 147456);        //   49152 B
  int*   cnt      = (int*)(ws + 196608);        //   16384 B
  int*   rowmap   = (int*)(ws + 212992);        //   65536 B
  int*   flagr    = (int*)(ws + 278528);        //   49152 B
  float* pv1      = (float*)(ws + 327680);      //  786432 B
  int*   pi1      = (int*)(ws + 1114112);       //  786432 B
  float* pv2      = (float*)(ws + 1900544);     //  786432 B
  float* xm       = (float*)(ws + 2686976);     // 16.78 MB
  float* qkvm     = (float*)(ws + 19464192);    // 50.33 MB
  float* om       = (float*)(ws + 69795840);    // 16.78 MB
  float* ym       = xm;                         // reuse (xm consumed by k_qkv)
  float* out      = (float*)d_out;

  hipMemsetAsync(cnt, 0, B_ * ND_ * sizeof(int), stream);
  k_init_indices<<<1, 1024, 0, stream>>>(b_idx, a_idx);
  k_row_norms<<<B_ * N_, 256, 0, stream>>>(x, dinv);
  k_scores<<<dim3(16, 48, B_), 256, 0, stream>>>(x, dinv, a_idx, b_idx, pv1, pi1, pv2);
  k_finalize<<<(B_ * NA_) / 256, 256, 0, stream>>>(pv1, pi1, pv2, node_idx, flagr);
  k_recheck<<<B_ * NA_, 256, 0, stream>>>(x, dinv, a_idx, b_idx, flagr, node_idx);
  k_counts_rowmap<<<(B_ * N_) / 256, 256, 0, stream>>>(a_idx, b_idx, node_idx, cnt, rowmap);
  k_merge_init<<<B_ * ND_, 256, 0, stream>>>(x, b_idx, xm);
  k_merge_add<<<B_ * NA_, 256, 0, stream>>>(x, a_idx, node_idx, xm);
  k_merge_scale<<<B_ * ND_, 256, 0, stream>>>(xm, cnt);
  k_qkv<<<dim3(24, 32), 256, 0, stream>>>(xm, Wqkv, qkvm);
  k_attn<<<dim3(16, 16, B_), 256, 0, stream>>>(qkvm, om);
  k_proj<<<dim3(8, 32), 256, 0, stream>>>(om, Wp, bp, ym);
  k_unmerge<<<B_ * N_, 256, 0, stream>>>(ym, rowmap, out);
}

// Round 9
// 1668.807 us; speedup vs baseline: 1.6626x; 1.6626x over previous
//
#include <hip/hip_runtime.h>
#include <cmath>

// Problem constants (B,N,DIM,HEADS)=(4,4096,1024,16), SX=SY=2, ratio .9
#define B_  4
#define N_  4096
#define C_  1024
#define H_  16
#define D_  64
#define ND_ 1024   // num dst tokens (one per 2x2 block)
#define NA_ 3072   // num src (a) tokens
// r = min(3072, int(4096*0.9)) = 3072  => unm empty, sort permutation cancels.

// ---------------------------------------------------------------------------
// threefry2x32 (20 rounds), returns BOTH output words.
// ---------------------------------------------------------------------------
__device__ inline void tf2x32(unsigned k0, unsigned k1, unsigned x0, unsigned x1,
                              unsigned& o0, unsigned& o1) {
  const unsigned ks2 = 0x1BD11BDAu ^ k0 ^ k1;
  x0 += k0; x1 += k1;
#define RND_(r) { x0 += x1; x1 = (x1 << (r)) | (x1 >> (32 - (r))); x1 ^= x0; }
  RND_(13) RND_(15) RND_(26) RND_(6)
  x0 += k1;  x1 += ks2 + 1u;
  RND_(17) RND_(29) RND_(16) RND_(24)
  x0 += ks2; x1 += k0 + 2u;
  RND_(13) RND_(15) RND_(26) RND_(6)
  x0 += k0;  x1 += k1 + 3u;
  RND_(17) RND_(29) RND_(16) RND_(24)
  x0 += k1;  x1 += ks2 + 4u;
  RND_(13) RND_(15) RND_(26) RND_(6)
  x0 += ks2; x1 += k0 + 5u;
#undef RND_
  o0 = x0; o1 = x1;
}

// ---------------------------------------------------------------------------
// K1 (VERIFIED r7): jax.random.randint(key(33),(32,32),0,4):
// k2 = split(key)[1] = threefry_out((0,33),(0,1)); element p ->
// threefry(k2,(0,p)), value = (bits1^bits2) & 3.
// ---------------------------------------------------------------------------
__global__ __launch_bounds__(1024) void k_init_indices(int* __restrict__ b_idx,
                                                       int* __restrict__ a_idx) {
  __shared__ unsigned char randk[1024];
  __shared__ int wtot[16], wpre[16];
  const int tid = threadIdx.x;
  {
    unsigned c0, c1;
    tf2x32(0u, 33u, 0u, 1u, c0, c1);                 // k2 = split(key)[1]
    unsigned d0, d1;
    tf2x32(c0, c1, 0u, (unsigned)tid, d0, d1);       // random_bits element p
    randk[tid] = (unsigned char)((d0 ^ d1) & 3u);    // xor-fold, % span
  }
  __syncthreads();
  const int base_t = tid * 4;
  int f[4]; int cnt = 0;
#pragma unroll
  for (int j = 0; j < 4; j++) {
    const int t = base_t + j;
    const int y = t >> 6, xc = t & 63;
    const int bi = (y >> 1) * 32 + (xc >> 1);
    const int k  = (y & 1) * 2 + (xc & 1);
    f[j] = (randk[bi] == (unsigned char)k) ? 1 : 0;
    cnt += f[j];
  }
  const int lane = tid & 63, wave = tid >> 6;
  int incl = cnt;
#pragma unroll
  for (int off = 1; off < 64; off <<= 1) {
    int nb = __shfl_up(incl, off, 64);
    if (lane >= off) incl += nb;
  }
  if (lane == 63) wtot[wave] = incl;
  __syncthreads();
  if (tid == 0) { int s = 0; for (int w = 0; w < 16; w++) { wpre[w] = s; s += wtot[w]; } }
  __syncthreads();
  int P = wpre[wave] + (incl - cnt);   // #dst strictly before base_t
#pragma unroll
  for (int j = 0; j < 4; j++) {
    const int t = base_t + j;
    if (f[j]) { b_idx[P] = t; P++; }
    else      { a_idx[t - P] = t; }
  }
}

// ---------------------------------------------------------------------------
// K2: per-token inverse L2 norm of x, fp64
// ---------------------------------------------------------------------------
__global__ __launch_bounds__(256) void k_row_norms(const float* __restrict__ x,
                                                   double* __restrict__ dinv) {
  const int row = blockIdx.x;                 // B_*N_
  const float* xr = x + (size_t)row * C_;
  const int tid = threadIdx.x;
  float4 v = ((const float4*)xr)[tid];
  double s = (double)v.x * (double)v.x + (double)v.y * (double)v.y +
             (double)v.z * (double)v.z + (double)v.w * (double)v.w;
#pragma unroll
  for (int off = 32; off; off >>= 1) s += __shfl_down(s, off, 64);
  __shared__ double wsum[4];
  if ((tid & 63) == 0) wsum[tid >> 6] = s;
  __syncthreads();
  if (tid == 0) {
    double t = wsum[0] + wsum[1] + wsum[2] + wsum[3];
    dinv[row] = 1.0 / sqrt(t);
  }
}

// top-2 merge tracking both indices
__device__ inline void top2m(float& v1, int& i1, float& v2, int& i2,
                             float ov1, int oi1, float ov2, int oi2) {
  if (ov1 > v1 || (ov1 == v1 && oi1 < i1)) {
    if (v1 > ov2 || (v1 == ov2 && i1 < oi2)) { v2 = v1; i2 = i1; }
    else { v2 = ov2; i2 = oi2; }
    v1 = ov1; i1 = oi1;
  } else if (ov1 > v2 || (ov1 == v2 && oi1 < i2)) {
    v2 = ov1; i2 = oi1;
  }
}

// ---------------------------------------------------------------------------
// K3: fp32 scores 64x64 tile GEMM, top-2 (values+indices) epilogue.
// ---------------------------------------------------------------------------
__global__ __launch_bounds__(256) void k_scores(
    const float* __restrict__ x, const double* __restrict__ dinv,
    const int* __restrict__ a_idx, const int* __restrict__ b_idx,
    float* __restrict__ pv1, int* __restrict__ pi1,
    float* __restrict__ pv2, int* __restrict__ pi2) {
  __shared__ __align__(16) float As[16][68];
  __shared__ __align__(16) float Bs[16][68];
  const int bz = blockIdx.z, cb = blockIdx.x, sb = blockIdx.y;
  const int tid = threadIdx.x;
  const int tx = tid & 15, ty = tid >> 4;
  const int lm = tid >> 2, lk = (tid & 3) * 4;
  const int ga = a_idx[sb * 64 + lm];
  const int gb = b_idx[cb * 64 + lm];
  const float ia = (float)dinv[bz * N_ + ga];
  const float ib = (float)dinv[bz * N_ + gb];
  const float* __restrict__ xa = x + ((size_t)bz * N_ + ga) * C_;
  const float* __restrict__ xb = x + ((size_t)bz * N_ + gb) * C_;
  float acc[4][4] = {};
  for (int k0 = 0; k0 < C_; k0 += 16) {
    const float4 av = *(const float4*)(xa + k0 + lk);
    const float4 bv = *(const float4*)(xb + k0 + lk);
    __syncthreads();
    As[lk + 0][lm] = av.x * ia; As[lk + 1][lm] = av.y * ia;
    As[lk + 2][lm] = av.z * ia; As[lk + 3][lm] = av.w * ia;
    Bs[lk + 0][lm] = bv.x * ib; Bs[lk + 1][lm] = bv.y * ib;
    Bs[lk + 2][lm] = bv.z * ib; Bs[lk + 3][lm] = bv.w * ib;
    __syncthreads();
#pragma unroll
    for (int k = 0; k < 16; k++) {
      const float4 a4 = *(const float4*)&As[k][ty * 4];
      const float4 b4 = *(const float4*)&Bs[k][tx * 4];
      const float ar[4] = {a4.x, a4.y, a4.z, a4.w};
      const float br[4] = {b4.x, b4.y, b4.z, b4.w};
#pragma unroll
      for (int i = 0; i < 4; i++)
#pragma unroll
        for (int j = 0; j < 4; j++) acc[i][j] = fmaf(ar[i], br[j], acc[i][j]);
    }
  }
#pragma unroll
  for (int i = 0; i < 4; i++) {
    float v1 = acc[i][0]; int i1 = cb * 64 + tx * 4;
    float v2 = -INFINITY; int i2 = i1;
#pragma unroll
    for (int j = 1; j < 4; j++) {
      const float v = acc[i][j];
      const int d = cb * 64 + tx * 4 + j;
      if (v > v1) { v2 = v1; i2 = i1; v1 = v; i1 = d; }
      else if (v > v2) { v2 = v; i2 = d; }
    }
#pragma unroll
    for (int off = 8; off; off >>= 1) {
      const float ov1 = __shfl_xor(v1, off, 16);
      const int   oi1 = __shfl_xor(i1, off, 16);
      const float ov2 = __shfl_xor(v2, off, 16);
      const int   oi2 = __shfl_xor(i2, off, 16);
      top2m(v1, i1, v2, i2, ov1, oi1, ov2, oi2);
    }
    if (tx == 0) {
      const int s = sb * 64 + ty * 4 + i;
      const size_t o = ((size_t)bz * NA_ + s) * 16 + cb;
      pv1[o] = v1; pi1[o] = i1; pv2[o] = v2; pi2[o] = i2;
    }
  }
}

// K4: merge 16 per-tile partials -> node_idx + near-tie flag
__global__ __launch_bounds__(256) void k_finalize(
    const float* __restrict__ pv1, const int* __restrict__ pi1,
    const float* __restrict__ pv2, const int* __restrict__ pi2,
    int* __restrict__ node_idx, int* __restrict__ flagr) {
  const int r = blockIdx.x * 256 + threadIdx.x;   // [0, B_*NA_)
  if (r >= B_ * NA_) return;
  size_t o = (size_t)r * 16;
  float v1 = pv1[o]; int i1 = pi1[o]; float v2 = pv2[o]; int i2 = pi2[o];
  for (int cb = 1; cb < 16; cb++)
    top2m(v1, i1, v2, i2, pv1[o + cb], pi1[o + cb], pv2[o + cb], pi2[o + cb]);
  node_idx[r] = i1;
  flagr[r] = (v1 - v2 < 3e-4f) ? 1 : 0;  // fp32 GEMM error ~1e-5 << 3e-4
}

// ---------------------------------------------------------------------------
// K5: candidate-based fp64 recheck for flagged rows.
// Candidates: per-tile top1 always; top2 if within 3e-4 of global v1;
// full 64-dst tile scan if tile v2 within 5e-5 of v1 (covers >=3-way ties).
// ---------------------------------------------------------------------------
__global__ __launch_bounds__(256) void k_recheck(
    const float* __restrict__ x, const double* __restrict__ dinv,
    const int* __restrict__ a_idx, const int* __restrict__ b_idx,
    const float* __restrict__ pv1, const int* __restrict__ pi1,
    const float* __restrict__ pv2, const int* __restrict__ pi2,
    const int* __restrict__ flagr, int* __restrict__ node_idx) {
  const int r = blockIdx.x;                 // bz*NA_ + s
  if (!flagr[r]) return;
  const int bz = r / NA_, s = r % NA_;
  __shared__ double arow[C_];
  __shared__ int cand[1088];
  __shared__ int ncand;
  __shared__ float v1s[16];
  const int tid = threadIdx.x;
  const int ga = a_idx[s];
  const double ia = dinv[bz * N_ + ga];
  const float* xa = x + ((size_t)bz * N_ + ga) * C_;
  for (int c = tid; c < C_; c += 256) arow[c] = (double)xa[c] * ia;
  const size_t o = (size_t)r * 16;
  if (tid < 16) v1s[tid] = pv1[o + tid];
  if (tid == 0) ncand = 0;
  __syncthreads();
  // global fp32 v1
  float v1g = v1s[0];
#pragma unroll
  for (int cb = 1; cb < 16; cb++) v1g = fmaxf(v1g, v1s[cb]);
  // build candidate list (threads 0..15 handle one tile each)
  if (tid < 16) {
    const float tv1 = pv1[o + tid], tv2 = pv2[o + tid];
    if (tv2 >= v1g - 5e-5f) {
      // rare: >=2 near-max in one tile -> scan whole tile
      const int base = atomicAdd(&ncand, 64);
      for (int j = 0; j < 64; j++) cand[base + j] = tid * 64 + j;
    } else {
      if (tv1 >= v1g - 3e-4f) { cand[atomicAdd(&ncand, 1)] = pi1[o + tid]; }
      if (tv2 >= v1g - 3e-4f) { cand[atomicAdd(&ncand, 1)] = pi2[o + tid]; }
    }
  }
  __syncthreads();
  const int nc = ncand;
  const int lane = tid & 63, wave = tid >> 6;
  double bv = -1e300; int bi = 1 << 30;
  for (int ci = wave; ci < nc; ci += 4) {
    const int d = cand[ci];
    const int gb = b_idx[d];
    const double ib = dinv[bz * N_ + gb];
    const float* xb = x + ((size_t)bz * N_ + gb) * C_;
    double sum = 0.0;
    for (int c = lane; c < C_; c += 64) sum += arow[c] * ((double)xb[c] * ib);
#pragma unroll
    for (int off = 32; off; off >>= 1) sum += __shfl_xor(sum, off, 64);
    if (sum > bv || (sum == bv && d < bi)) { bv = sum; bi = d; }
  }
  __shared__ double bvs[4]; __shared__ int bis[4];
  if (lane == 0) { bvs[wave] = bv; bis[wave] = bi; }
  __syncthreads();
  if (tid == 0) {
    for (int w = 1; w < 4; w++)
      if (bvs[w] > bv || (bvs[w] == bv && bis[w] < bi)) { bv = bvs[w]; bi = bis[w]; }
    node_idx[r] = bi;
  }
}

// K6: counts per dst + token->merged-row map
__global__ __launch_bounds__(256) void k_counts_rowmap(
    const int* __restrict__ a_idx, const int* __restrict__ b_idx,
    const int* __restrict__ node_idx, int* __restrict__ cnt,
    int* __restrict__ rowmap) {
  const int i = blockIdx.x * 256 + threadIdx.x;   // [0, B_*N_)
  if (i >= B_ * N_) return;
  const int bz = i >> 12, j = i & 4095;
  if (j < NA_) {
    const int nd = node_idx[bz * NA_ + j];
    atomicAdd(&cnt[bz * ND_ + nd], 1);
    rowmap[bz * N_ + a_idx[j]] = nd;
  } else {
    const int d = j - NA_;
    rowmap[bz * N_ + b_idx[d]] = d;
  }
}

// K7/K8/K9: merge x into xm
__global__ __launch_bounds__(256) void k_merge_init(const float* __restrict__ x,
                                                    const int* __restrict__ b_idx,
                                                    float* __restrict__ xm) {
  const int blk = blockIdx.x;                 // B_*ND_
  const int bz = blk >> 10, d = blk & 1023;
  const float4* src = (const float4*)(x + ((size_t)bz * N_ + b_idx[d]) * C_);
  float4* dst = (float4*)(xm + ((size_t)bz * ND_ + d) * C_);
  dst[threadIdx.x] = src[threadIdx.x];
}

__global__ __launch_bounds__(256) void k_merge_add(const float* __restrict__ x,
                                                   const int* __restrict__ a_idx,
                                                   const int* __restrict__ node_idx,
                                                   float* __restrict__ xm) {
  const int blk = blockIdx.x;                 // B_*NA_ = bz*NA_+i
  const int bz = blk / NA_, i = blk % NA_;
  const int nd = node_idx[blk];
  const float* src = x + ((size_t)bz * N_ + a_idx[i]) * C_;
  float* dst = xm + ((size_t)bz * ND_ + nd) * C_;
  const int c0 = threadIdx.x * 4;
  const float4 v = *(const float4*)(src + c0);
  atomicAdd(&dst[c0 + 0], v.x);
  atomicAdd(&dst[c0 + 1], v.y);
  atomicAdd(&dst[c0 + 2], v.z);
  atomicAdd(&dst[c0 + 3], v.w);
}

__global__ __launch_bounds__(256) void k_merge_scale(float* __restrict__ xm,
                                                     const int* __restrict__ cnt) {
  const int blk = blockIdx.x;                 // B_*ND_
  const float s = 1.0f + (float)cnt[blk];
  float4* p = (float4*)(xm + (size_t)blk * C_);
  float4 v = p[threadIdx.x];
  v.x /= s; v.y /= s; v.z /= s; v.w /= s;
  p[threadIdx.x] = v;
}

// ---------------------------------------------------------------------------
// K10: qkv GEMM, 128x128 tile, 8x8 per thread, BK=8.
// qkvm[b][w][h][t][d] = xm @ W_qkv^T   (M=4096, N=3072, K=1024)
// ---------------------------------------------------------------------------
__global__ __launch_bounds__(256) void k_qkv(const float* __restrict__ xm,
                                             const float* __restrict__ Wqkv,
                                             float* __restrict__ qkvm) {
  __shared__ __align__(16) float As[8][132];
  __shared__ __align__(16) float Bs[8][132];
  const int nb = blockIdx.x;   // 24
  const int mb = blockIdx.y;   // 32
  const int tid = threadIdx.x;
  const int tx = tid & 15, ty = tid >> 4;
  const int lr = tid >> 1;            // 0..127
  const int lkc = (tid & 1) * 4;      // 0 or 4
  const float* __restrict__ ar = xm + (size_t)(mb * 128 + lr) * C_ + lkc;
  const float* __restrict__ br = Wqkv + (size_t)(nb * 128 + lr) * C_ + lkc;
  float acc[8][8] = {};
  for (int k0 = 0; k0 < C_; k0 += 8) {
    const float4 av = *(const float4*)(ar + k0);
    const float4 bv = *(const float4*)(br + k0);
    __syncthreads();
    As[lkc + 0][lr] = av.x; As[lkc + 1][lr] = av.y;
    As[lkc + 2][lr] = av.z; As[lkc + 3][lr] = av.w;
    Bs[lkc + 0][lr] = bv.x; Bs[lkc + 1][lr] = bv.y;
    Bs[lkc + 2][lr] = bv.z; Bs[lkc + 3][lr] = bv.w;
    __syncthreads();
#pragma unroll
    for (int k = 0; k < 8; k++) {
      float a_[8], b_[8];
      *(float4*)&a_[0] = *(const float4*)&As[k][ty * 8];
      *(float4*)&a_[4] = *(const float4*)&As[k][ty * 8 + 4];
      *(float4*)&b_[0] = *(const float4*)&Bs[k][tx * 8];
      *(float4*)&b_[4] = *(const float4*)&Bs[k][tx * 8 + 4];
#pragma unroll
      for (int i = 0; i < 8; i++)
#pragma unroll
        for (int j = 0; j < 8; j++) acc[i][j] = fmaf(a_[i], b_[j], acc[i][j]);
    }
  }
  const int n0 = nb * 128 + tx * 8;
  const int w = n0 >> 10, h = (n0 >> 6) & 15, dc = n0 & 63;   // 8 cols within 1 head
#pragma unroll
  for (int i = 0; i < 8; i++) {
    const int m = mb * 128 + ty * 8 + i;
    const int bb = m >> 10, t = m & 1023;
    float* dst = qkvm + (((size_t)(bb * 3 + w) * 16 + h) * 1024 + t) * 64 + dc;
    *(float4*)dst       = make_float4(acc[i][0], acc[i][1], acc[i][2], acc[i][3]);
    *(float4*)(dst + 4) = make_float4(acc[i][4], acc[i][5], acc[i][6], acc[i][7]);
  }
}

// ---------------------------------------------------------------------------
// K11: flash attention, transposed LDS (vector ds_read in both inner loops)
// ---------------------------------------------------------------------------
__global__ __launch_bounds__(256) void k_attn(const float* __restrict__ qkvm,
                                              float* __restrict__ om) {
  __shared__ float qsT[64][65];   // [d][token]
  __shared__ float ksT[64][65];   // [d][token]
  __shared__ float vs[64][65];    // [token][d]
  __shared__ float psT[64][65];   // [kcol][qrow]
  __shared__ float mi[64], li[64];
  const int qb = blockIdx.x, h = blockIdx.y, bz = blockIdx.z;
  const int tid = threadIdx.x;
  const int tx = tid & 15, ty = tid >> 4;
  const float* __restrict__ qp = qkvm + (((size_t)(bz * 3 + 0) * 16 + h) * 1024) * 64;
  const float* __restrict__ kp = qkvm + (((size_t)(bz * 3 + 1) * 16 + h) * 1024) * 64;
  const float* __restrict__ vp = qkvm + (((size_t)(bz * 3 + 2) * 16 + h) * 1024) * 64;
  const int lr = tid >> 2, lc = (tid & 3) * 16;
  {
    const float4* src = (const float4*)(qp + (size_t)(qb * 64 + lr) * 64 + lc);
#pragma unroll
    for (int j = 0; j < 4; j++) {
      const float4 v4 = src[j];
      qsT[lc + j * 4 + 0][lr] = v4.x * 0.125f;
      qsT[lc + j * 4 + 1][lr] = v4.y * 0.125f;
      qsT[lc + j * 4 + 2][lr] = v4.z * 0.125f;
      qsT[lc + j * 4 + 3][lr] = v4.w * 0.125f;
    }
  }
  if (tid < 64) { mi[tid] = -INFINITY; li[tid] = 0.0f; }
  float o[4][4] = {};
  float mnew[4], alpha[4], psum[4];
  for (int kt = 0; kt < 16; kt++) {
    __syncthreads();
    {
      const float4* ksrc = (const float4*)(kp + (size_t)(kt * 64 + lr) * 64 + lc);
      const float4* vsrc = (const float4*)(vp + (size_t)(kt * 64 + lr) * 64 + lc);
#pragma unroll
      for (int j = 0; j < 4; j++) {
        const float4 kv = ksrc[j], vv = vsrc[j];
        ksT[lc + j * 4 + 0][lr] = kv.x; ksT[lc + j * 4 + 1][lr] = kv.y;
        ksT[lc + j * 4 + 2][lr] = kv.z; ksT[lc + j * 4 + 3][lr] = kv.w;
        vs[lr][lc + j * 4 + 0] = vv.x; vs[lr][lc + j * 4 + 1] = vv.y;
        vs[lr][lc + j * 4 + 2] = vv.z; vs[lr][lc + j * 4 + 3] = vv.w;
      }
    }
    __syncthreads();
    float sacc[4][4] = {};
#pragma unroll 4
    for (int c = 0; c < 64; c++) {
      const float4 a4 = *(const float4*)&qsT[c][ty * 4];
      const float4 b4 = *(const float4*)&ksT[c][tx * 4];
      const float a_[4] = {a4.x, a4.y, a4.z, a4.w};
      const float b_[4] = {b4.x, b4.y, b4.z, b4.w};
#pragma unroll
      for (int i = 0; i < 4; i++)
#pragma unroll
        for (int j = 0; j < 4; j++) sacc[i][j] = fmaf(a_[i], b_[j], sacc[i][j]);
    }
#pragma unroll
    for (int i = 0; i < 4; i++) {
      float tmax = fmaxf(fmaxf(sacc[i][0], sacc[i][1]), fmaxf(sacc[i][2], sacc[i][3]));
#pragma unroll
      for (int off = 8; off; off >>= 1) tmax = fmaxf(tmax, __shfl_xor(tmax, off, 16));
      const float mold = mi[ty * 4 + i];
      const float mn = fmaxf(mold, tmax);
      mnew[i] = mn;
      alpha[i] = expf(mold - mn);
      float s_ = 0.0f;
#pragma unroll
      for (int j = 0; j < 4; j++) { sacc[i][j] = expf(sacc[i][j] - mn); s_ += sacc[i][j]; }
#pragma unroll
      for (int off = 8; off; off >>= 1) s_ += __shfl_xor(s_, off, 16);
      psum[i] = s_;
#pragma unroll
      for (int j = 0; j < 4; j++) psT[tx * 4 + j][ty * 4 + i] = sacc[i][j];
    }
    __syncthreads();
    if (tx == 0) {
#pragma unroll
      for (int i = 0; i < 4; i++) {
        mi[ty * 4 + i] = mnew[i];
        li[ty * 4 + i] = li[ty * 4 + i] * alpha[i] + psum[i];
      }
    }
#pragma unroll
    for (int i = 0; i < 4; i++)
#pragma unroll
      for (int j = 0; j < 4; j++) o[i][j] *= alpha[i];
#pragma unroll 4
    for (int d2 = 0; d2 < 64; d2++) {
      const float4 p4 = *(const float4*)&psT[d2][ty * 4];
      const float4 v4 = *(const float4*)&vs[d2][tx * 4];
      const float pr[4] = {p4.x, p4.y, p4.z, p4.w};
      const float vr[4] = {v4.x, v4.y, v4.z, v4.w};
#pragma unroll
      for (int i = 0; i < 4; i++)
#pragma unroll
        for (int j = 0; j < 4; j++) o[i][j] = fmaf(pr[i], vr[j], o[i][j]);
    }
  }
  __syncthreads();
#pragma unroll
  for (int i = 0; i < 4; i++) {
    const float inv = 1.0f / li[ty * 4 + i];
    const int t = qb * 64 + ty * 4 + i;
    const float4 st = make_float4(o[i][0] * inv, o[i][1] * inv, o[i][2] * inv, o[i][3] * inv);
    *(float4*)(om + ((size_t)bz * ND_ + t) * C_ + h * 64 + tx * 4) = st;
  }
}

// ---------------------------------------------------------------------------
// K12: proj GEMM, 128x128 tile, 8x8 per thread, BK=8. ym = om@Wp^T + bp
// ---------------------------------------------------------------------------
__global__ __launch_bounds__(256) void k_proj(const float* __restrict__ om,
                                              const float* __restrict__ Wp,
                                              const float* __restrict__ bp,
                                              float* __restrict__ ym) {
  __shared__ __align__(16) float As[8][132];
  __shared__ __align__(16) float Bs[8][132];
  const int nb = blockIdx.x;   // 8
  const int mb = blockIdx.y;   // 32
  const int tid = threadIdx.x;
  const int tx = tid & 15, ty = tid >> 4;
  const int lr = tid >> 1;
  const int lkc = (tid & 1) * 4;
  const float* __restrict__ ar = om + (size_t)(mb * 128 + lr) * C_ + lkc;
  const float* __restrict__ br = Wp + (size_t)(nb * 128 + lr) * C_ + lkc;
  float acc[8][8] = {};
  for (int k0 = 0; k0 < C_; k0 += 8) {
    const float4 av = *(const float4*)(ar + k0);
    const float4 bv = *(const float4*)(br + k0);
    __syncthreads();
    As[lkc + 0][lr] = av.x; As[lkc + 1][lr] = av.y;
    As[lkc + 2][lr] = av.z; As[lkc + 3][lr] = av.w;
    Bs[lkc + 0][lr] = bv.x; Bs[lkc + 1][lr] = bv.y;
    Bs[lkc + 2][lr] = bv.z; Bs[lkc + 3][lr] = bv.w;
    __syncthreads();
#pragma unroll
    for (int k = 0; k < 8; k++) {
      float a_[8], b_[8];
      *(float4*)&a_[0] = *(const float4*)&As[k][ty * 8];
      *(float4*)&a_[4] = *(const float4*)&As[k][ty * 8 + 4];
      *(float4*)&b_[0] = *(const float4*)&Bs[k][tx * 8];
      *(float4*)&b_[4] = *(const float4*)&Bs[k][tx * 8 + 4];
#pragma unroll
      for (int i = 0; i < 8; i++)
#pragma unroll
        for (int j = 0; j < 8; j++) acc[i][j] = fmaf(a_[i], b_[j], acc[i][j]);
    }
  }
  const int n0 = nb * 128 + tx * 8;
  const float4 b0 = *(const float4*)(bp + n0);
  const float4 b1 = *(const float4*)(bp + n0 + 4);
#pragma unroll
  for (int i = 0; i < 8; i++) {
    const int m = mb * 128 + ty * 8 + i;
    float* dst = ym + (size_t)m * C_ + n0;
    *(float4*)dst       = make_float4(acc[i][0] + b0.x, acc[i][1] + b0.y,
                                      acc[i][2] + b0.z, acc[i][3] + b0.w);
    *(float4*)(dst + 4) = make_float4(acc[i][4] + b1.x, acc[i][5] + b1.y,
                                      acc[i][6] + b1.z, acc[i][7] + b1.w);
  }
}

// K13: scatter merged rows back to all 4096 tokens
__global__ __launch_bounds__(256) void k_unmerge(const float* __restrict__ ym,
                                                 const int* __restrict__ rowmap,
                                                 float* __restrict__ out) {
  const int blk = blockIdx.x;                 // B_*N_
  const int bz = blk >> 12;
  const int r = rowmap[blk];
  const float4* src = (const float4*)(ym + ((size_t)bz * ND_ + r) * C_);
  float4* dst = (float4*)(out + (size_t)blk * C_);
  dst[threadIdx.x] = src[threadIdx.x];
}

// ---------------------------------------------------------------------------
extern "C" void kernel_launch(void* const* d_in, const int* in_sizes, int n_in,
                              void* d_out, int out_size, void* d_ws, size_t ws_size,
                              hipStream_t stream) {
  const float* x    = (const float*)d_in[0];
  const float* Wqkv = (const float*)d_in[1];
  const float* Wp   = (const float*)d_in[2];
  const float* bp   = (const float*)d_in[3];
  char* ws = (char*)d_ws;
  double* dinv    = (double*)(ws + 0);          //  131072 B
  int*   b_idx    = (int*)(ws + 131072);        //    4096 B
  int*   a_idx    = (int*)(ws + 135168);        //   12288 B
  int*   node_idx = (int*)(ws + 147456);        //   49152 B
  int*   cnt      = (int*)(ws + 196608);        //   16384 B
  int*   rowmap   = (int*)(ws + 212992);        //   65536 B
  int*   flagr    = (int*)(ws + 278528);        //   49152 B
  float* pv1      = (float*)(ws + 327680);      //  786432 B
  int*   pi1      = (int*)(ws + 1114112);       //  786432 B
  float* pv2      = (float*)(ws + 1900544);     //  786432 B
  int*   pi2      = (int*)(ws + 2686976);       //  786432 B
  float* xm       = (float*)(ws + 3473408);     // 16.78 MB
  float* qkvm     = (float*)(ws + 20250624);    // 50.33 MB
  float* om       = (float*)(ws + 70582272);    // 16.78 MB
  float* ym       = xm;                         // reuse (xm consumed by k_qkv)
  float* out      = (float*)d_out;

  hipMemsetAsync(cnt, 0, B_ * ND_ * sizeof(int), stream);
  k_init_indices<<<1, 1024, 0, stream>>>(b_idx, a_idx);
  k_row_norms<<<B_ * N_, 256, 0, stream>>>(x, dinv);
  k_scores<<<dim3(16, 48, B_), 256, 0, stream>>>(x, dinv, a_idx, b_idx, pv1, pi1, pv2, pi2);
  k_finalize<<<(B_ * NA_) / 256, 256, 0, stream>>>(pv1, pi1, pv2, pi2, node_idx, flagr);
  k_recheck<<<B_ * NA_, 256, 0, stream>>>(x, dinv, a_idx, b_idx, pv1, pi1, pv2, pi2, flagr, node_idx);
  k_counts_rowmap<<<(B_ * N_) / 256, 256, 0, stream>>>(a_idx, b_idx, node_idx, cnt, rowmap);
  k_merge_init<<<B_ * ND_, 256, 0, stream>>>(x, b_idx, xm);
  k_merge_add<<<B_ * NA_, 256, 0, stream>>>(x, a_idx, node_idx, xm);
  k_merge_scale<<<B_ * ND_, 256, 0, stream>>>(xm, cnt);
  k_qkv<<<dim3(24, 32), 256, 0, stream>>>(xm, Wqkv, qkvm);
  k_attn<<<dim3(16, 16, B_), 256, 0, stream>>>(qkvm, om);
  k_proj<<<dim3(8, 32), 256, 0, stream>>>(om, Wp, bp, ym);
  k_unmerge<<<B_ * N_, 256, 0, stream>>>(ym, rowmap, out);
}